// Round 23
// baseline (405.985 us; speedup 1.0000x reference)
//
#include <hip/hip_runtime.h>
#include <hip/hip_bf16.h>
#include <math.h>

#define NNODES 50000
#define NEDGES 800000
#define DIM 128
#define NH 8

#define NEG_SENTINEL -3.0e38f

typedef __attribute__((ext_vector_type(8))) short bf16x8_t;
typedef __attribute__((ext_vector_type(4))) float f32x4_t;

__device__ __forceinline__ float gelu_exact(float v) {
    return 0.5f * v * (1.0f + erff(v * 0.70710678118654752f));
}
__device__ __forceinline__ ushort bfbits(float f) {
    uint u = __float_as_uint(f);
    u += 0x7fffu + ((u >> 16) & 1u);
    return (ushort)(u >> 16);
}
__device__ __forceinline__ uint pack2(float a, float b) {
    return (uint)bfbits(a) | ((uint)bfbits(b) << 16);
}
__device__ __forceinline__ float lo16(uint u) { return __uint_as_float(u << 16); }
__device__ __forceinline__ float hi16(uint u) { return __uint_as_float(u & 0xffff0000u); }
__device__ __forceinline__ float b2f(ushort u) { return __uint_as_float(((uint)u) << 16); }

// cooperative weight-stage helpers (16KB stage = 64 rows x 128 k bf16, XOR-swizzled)
__device__ __forceinline__ void stage_load(const ushort* base, int strideRow, uint4* wreg, int tid) {
    #pragma unroll
    for (int it = 0; it < 4; ++it) {
        int idx = it * 256 + tid;
        int col = idx >> 4, ch = idx & 15;
        wreg[it] = *reinterpret_cast<const uint4*>(base + (size_t)col * strideRow + ch * 8);
    }
}
__device__ __forceinline__ void stage_write(char* WsB, const uint4* wreg, int tid) {
    #pragma unroll
    for (int it = 0; it < 4; ++it) {
        int idx = it * 256 + tid;
        int col = idx >> 4, ch = idx & 15;
        *reinterpret_cast<uint4*>(WsB + col * 256 + ((ch * 16) ^ ((col & 7) << 4))) = wreg[it];
    }
}
// wo_ffn stage s (0..17) -> weight pointer + row stride
__device__ __forceinline__ const ushort* wf_stage_ptr(int s, const ushort* woT,
                                                      const ushort* w1t, const ushort* w2t,
                                                      int* stride) {
    if (s < 2) { *stride = 128; return woT + (size_t)s * 64 * 128; }
    int t = s - 2; int q = t >> 2, k = t & 3;
    if (k < 2) { *stride = 128; return w1t + (size_t)(q * 128 + k * 64) * 128; }
    *stride = 512; return w2t + (size_t)(k - 2) * 64 * 512 + q * 128;
}

// ---------------- zero counts (+done_ctr) ----------------
__global__ void zero_counts(int* __restrict__ counts) {
    int i = blockIdx.x * 256 + threadIdx.x;
    if (i < NNODES + 1) counts[i] = 0;
}

// ---------------- setup: edge histogram (+rank) + weight transpose/convert + bias pack ----------------
__global__ void setup_kernel(const int* __restrict__ ei, int* __restrict__ counts,
                             int* __restrict__ rank,
                             const float* __restrict__ Wq, const float* __restrict__ Wk,
                             const float* __restrict__ Wv, const float* __restrict__ Wo,
                             const float* __restrict__ W1, const float* __restrict__ W2,
                             const float* __restrict__ We,
                             const float* __restrict__ bq, const float* __restrict__ bk,
                             const float* __restrict__ bv,
                             ushort* __restrict__ wt4, ushort* __restrict__ w1t,
                             ushort* __restrict__ w2t, ushort* __restrict__ wet,
                             float* __restrict__ b384) {
    int b = blockIdx.x;
    if (b < NEDGES / 256) {
        int e = b * 256 + threadIdx.x;
        rank[e] = atomicAdd(&counts[ei[e]], 1);   // rank within row (order arbitrary)
        return;
    }
    int i = (b - NEDGES / 256) * 256 + threadIdx.x;
    if (i < 65536) {
        int w = i >> 14, j = i & 16383;
        int c = j >> 7, k = j & 127;
        const float* src = (w == 0) ? Wq : (w == 1) ? Wk : (w == 2) ? Wv : Wo;
        wt4[i] = bfbits(src[k * 128 + c]);
    } else if (i < 131072) {
        int j = i - 65536;
        int c = j >> 7, k = j & 127;
        w1t[j] = bfbits(W1[k * 512 + c]);
    } else if (i < 196608) {
        int j = i - 131072;
        int c = j >> 9, k = j & 511;
        w2t[j] = bfbits(W2[k * 128 + c]);
    } else if (i < 198656) {
        int j = i - 196608;
        int h = j >> 7, k = j & 127;
        wet[j] = (h < 8) ? bfbits(We[k * 8 + h]) : (ushort)0;
    } else if (i < 198656 + 384) {
        int j = i - 198656;
        b384[j] = (j < 128) ? bq[j] : (j < 256) ? bk[j - 128] : bv[j - 256];
    }
}

// ---------------- Fused LN1 + QKV GEMM with PIPELINED LDS weight staging ----------------
__global__ __launch_bounds__(256)
void ln_qkv_kernel(const float* __restrict__ x, const float* __restrict__ g1,
                   const float* __restrict__ b1, const ushort* __restrict__ wt4,
                   const float* __restrict__ b384, ushort* __restrict__ Qb,
                   uint* __restrict__ KVp, int M) {
    __shared__ ushort An[64 * 128];   // swizzled bf16 xn tile; rows wave*16.. wave-private
    __shared__ ushort Ws[64 * 128];   // shared weight stage (16KB)
    int tid = threadIdx.x, lane = tid & 63, wave = tid >> 6;
    int row0b = blockIdx.x * 64;
    int sr = lane >> 4;
    int sl = lane & 15;
    char* WsB = reinterpret_cast<char*>(Ws);
    // prefetch weight stage 0 immediately (hides under the LN phase)
    uint4 wreg[4];
    stage_load(wt4, 128, wreg, tid);
    float4 ga = reinterpret_cast<const float4*>(g1)[sl * 2];
    float4 gb = reinterpret_cast<const float4*>(g1)[sl * 2 + 1];
    float4 ba = reinterpret_cast<const float4*>(b1)[sl * 2];
    float4 bbv = reinterpret_cast<const float4*>(b1)[sl * 2 + 1];
    #pragma unroll
    for (int g = 0; g < 4; ++g) {
        int rl = wave * 16 + g * 4 + sr;
        int srow = min(row0b + rl, M - 1);
        const float4* xp = reinterpret_cast<const float4*>(x + (size_t)srow * 128 + sl * 8);
        float4 a = xp[0], b = xp[1];
        float s  = ((a.x + a.y) + (a.z + a.w)) + ((b.x + b.y) + (b.z + b.w));
        float sq = ((a.x*a.x + a.y*a.y) + (a.z*a.z + a.w*a.w)) +
                   ((b.x*b.x + b.y*b.y) + (b.z*b.z + b.w*b.w));
        #pragma unroll
        for (int mm = 1; mm < 16; mm <<= 1) {
            s  += __shfl_xor(s, mm, 64);
            sq += __shfl_xor(sq, mm, 64);
        }
        float mean = s * (1.0f / DIM);
        float var  = sq * (1.0f / DIM) - mean * mean;
        float rs = rsqrtf(var + 1e-5f);
        uint4 pk;
        pk.x = pack2((a.x - mean) * rs * ga.x + ba.x, (a.y - mean) * rs * ga.y + ba.y);
        pk.y = pack2((a.z - mean) * rs * ga.z + ba.z, (a.w - mean) * rs * ga.w + ba.w);
        pk.z = pack2((b.x - mean) * rs * gb.x + bbv.x, (b.y - mean) * rs * gb.y + bbv.y);
        pk.w = pack2((b.z - mean) * rs * gb.z + bbv.z, (b.w - mean) * rs * gb.w + bbv.w);
        int byte = rl * 256 + ((sl * 16) ^ ((rl & 7) << 4));
        *reinterpret_cast<uint4*>(reinterpret_cast<char*>(An) + byte) = pk;
    }
    __builtin_amdgcn_wave_barrier();
    int er = lane & 15, kg = lane >> 4;
    int lrow = wave * 16 + er;
    int rsw = (er & 7) << 4;
    bf16x8_t afN[4];
    #pragma unroll
    for (int ks = 0; ks < 4; ++ks)
        afN[ks] = *reinterpret_cast<const bf16x8_t*>(
            reinterpret_cast<char*>(An) + lrow * 256 + ((ks * 64 + kg * 16) ^ rsw));
    f32x4_t acc[24];
    #pragma unroll
    for (int f = 0; f < 24; ++f) acc[f] = (f32x4_t){0.f, 0.f, 0.f, 0.f};
    // 6 pipelined stages of 64 weight columns
    #pragma unroll
    for (int st = 0; st < 6; ++st) {
        __syncthreads();
        stage_write(WsB, wreg, tid);
        if (st < 5) stage_load(wt4 + (size_t)(st + 1) * 64 * 128, 128, wreg, tid);
        __syncthreads();
        #pragma unroll
        for (int ks = 0; ks < 4; ++ks) {
            #pragma unroll
            for (int fl = 0; fl < 4; ++fl) {
                int fc = fl * 16 + er;
                bf16x8_t bfr = *reinterpret_cast<const bf16x8_t*>(
                    WsB + fc * 256 + ((ks * 64 + kg * 16) ^ ((fc & 7) << 4)));
                acc[st * 4 + fl] = __builtin_amdgcn_mfma_f32_16x16x32_bf16(afN[ks], bfr, acc[st * 4 + fl], 0, 0, 0);
            }
        }
    }
    #pragma unroll
    for (int f = 0; f < 24; ++f) {
        int col = (f >> 2) * 64 + (f & 3) * 16 + er;
        float bc = b384[col];
        #pragma unroll
        for (int r = 0; r < 4; ++r) {
            int row = row0b + wave * 16 + kg * 4 + r;
            if (row < M) {
                float v = acc[f][r] + bc;
                if (col < 128) {
                    Qb[(size_t)row * 128 + col] = bfbits(v);
                } else if (col < 256) {
                    reinterpret_cast<ushort*>(KVp + (size_t)row * 128 + (col - 128))[0] = bfbits(v);
                } else {
                    reinterpret_cast<ushort*>(KVp + (size_t)row * 128 + (col - 256))[1] = bfbits(v);
                }
            }
        }
    }
}

// ---------------- Wo + residual + LN2 + FFN with PIPELINED LDS weight staging ----------------
__global__ __launch_bounds__(256)
void wo_ffn_kernel(const ushort* __restrict__ A, const ushort* __restrict__ woT,
                   const float* __restrict__ bo, const float* __restrict__ xres,
                   const float* __restrict__ g2, const float* __restrict__ b2,
                   const ushort* __restrict__ w1t, const float* __restrict__ bf1,
                   const ushort* __restrict__ w2t, const float* __restrict__ bf2,
                   float* __restrict__ out, int M) {
    __shared__ ushort An[64 * 128];   // wave-private rows
    __shared__ ushort Hb[64 * 128];   // wave-private rows
    __shared__ ushort Ws[64 * 128];   // shared weight stage (16KB)
    int tid = threadIdx.x, lane = tid & 63, wave = tid >> 6;
    int row0 = blockIdx.x * 64 + wave * 16;
    int er = lane & 15, kg = lane >> 4;
    int arow = min(row0 + er, M - 1);
    char* WsB = reinterpret_cast<char*>(Ws);

    // prefetch weight stage 0 (Wo half 0)
    uint4 wreg[4];
    {
        int strd; const ushort* p = wf_stage_ptr(0, woT, w1t, w2t, &strd);
        stage_load(p, strd, wreg, tid);
    }

    f32x4_t acc[8];
    #pragma unroll
    for (int f = 0; f < 8; ++f) acc[f] = (f32x4_t){0.f, 0.f, 0.f, 0.f};
    bf16x8_t afA[4];
    #pragma unroll
    for (int ks = 0; ks < 4; ++ks)
        afA[ks] = *reinterpret_cast<const bf16x8_t*>(A + (size_t)arow * 128 + ks * 32 + kg * 8);

    // ---- Phase A: Wo GEMM (stages 0,1) ----
    #pragma unroll
    for (int hh = 0; hh < 2; ++hh) {
        __syncthreads();
        stage_write(WsB, wreg, tid);
        {
            int ns = hh + 1, strd;
            const ushort* p = wf_stage_ptr(ns, woT, w1t, w2t, &strd);
            stage_load(p, strd, wreg, tid);
        }
        __syncthreads();
        #pragma unroll
        for (int ks = 0; ks < 4; ++ks) {
            #pragma unroll
            for (int fl = 0; fl < 4; ++fl) {
                int fc = fl * 16 + er;
                bf16x8_t bfr = *reinterpret_cast<const bf16x8_t*>(
                    WsB + fc * 256 + ((ks * 64 + kg * 16) ^ ((fc & 7) << 4)));
                acc[hh * 4 + fl] = __builtin_amdgcn_mfma_f32_16x16x32_bf16(afA[ks], bfr, acc[hh * 4 + fl], 0, 0, 0);
            }
        }
    }
    // + bo + residual;  acc f -> col = (f>>2)*64 + (f&3)*16 + er
    float g2l[8], b2l[8];
    #pragma unroll
    for (int f = 0; f < 8; ++f) {
        int col = (f >> 2) * 64 + (f & 3) * 16 + er;
        float bc = bo[col];
        g2l[f] = g2[col]; b2l[f] = b2[col];
        #pragma unroll
        for (int r = 0; r < 4; ++r) {
            int row = min(row0 + kg * 4 + r, M - 1);
            acc[f][r] += bc + xres[(size_t)row * 128 + col];
        }
    }
    // LN2 -> An (wave-private)
    #pragma unroll
    for (int r = 0; r < 4; ++r) {
        float s = 0.f, sq = 0.f;
        #pragma unroll
        for (int f = 0; f < 8; ++f) { s += acc[f][r]; sq += acc[f][r] * acc[f][r]; }
        #pragma unroll
        for (int m = 1; m < 16; m <<= 1) {
            s  += __shfl_xor(s, m, 64);
            sq += __shfl_xor(sq, m, 64);
        }
        float mean = s * (1.0f / DIM);
        float var  = sq * (1.0f / DIM) - mean * mean;
        float rs = rsqrtf(var + 1e-5f);
        int rl = wave * 16 + kg * 4 + r;
        #pragma unroll
        for (int f = 0; f < 8; ++f) {
            int col = (f >> 2) * 64 + (f & 3) * 16 + er;
            float xv = (acc[f][r] - mean) * rs * g2l[f] + b2l[f];
            int byte = rl * 256 + ((col * 2) ^ ((rl & 7) << 4));
            *reinterpret_cast<ushort*>(reinterpret_cast<char*>(An) + byte) = bfbits(xv);
        }
    }
    __builtin_amdgcn_wave_barrier();

    int lrow = wave * 16 + er;
    int rsw = (lrow & 7) << 4;
    f32x4_t acc2[8];
    #pragma unroll
    for (int f = 0; f < 8; ++f) acc2[f] = (f32x4_t){0.f, 0.f, 0.f, 0.f};

    bf16x8_t afN[4];
    #pragma unroll
    for (int ks = 0; ks < 4; ++ks)
        afN[ks] = *reinterpret_cast<const bf16x8_t*>(
            reinterpret_cast<char*>(An) + lrow * 256 + ((ks * 64 + kg * 16) ^ rsw));

    for (int q = 0; q < 4; ++q) {
        // ---- FFN1 quarter q (stages 2+q*4+0, +1) ----
        f32x4_t acch[8];
        #pragma unroll
        for (int f = 0; f < 8; ++f) acch[f] = (f32x4_t){0.f, 0.f, 0.f, 0.f};
        #pragma unroll
        for (int hh = 0; hh < 2; ++hh) {
            __syncthreads();
            stage_write(WsB, wreg, tid);
            {
                int ns = 2 + q * 4 + hh + 1, strd;
                const ushort* p = wf_stage_ptr(ns, woT, w1t, w2t, &strd);
                stage_load(p, strd, wreg, tid);
            }
            __syncthreads();
            #pragma unroll
            for (int ks = 0; ks < 4; ++ks) {
                #pragma unroll
                for (int fl = 0; fl < 4; ++fl) {
                    int fc = fl * 16 + er;
                    bf16x8_t bfr = *reinterpret_cast<const bf16x8_t*>(
                        WsB + fc * 256 + ((ks * 64 + kg * 16) ^ ((fc & 7) << 4)));
                    acch[hh * 4 + fl] = __builtin_amdgcn_mfma_f32_16x16x32_bf16(afN[ks], bfr, acch[hh * 4 + fl], 0, 0, 0);
                }
            }
        }
        // gelu -> Hb
        #pragma unroll
        for (int f = 0; f < 8; ++f) {
            int colq = (f >> 2) * 64 + (f & 3) * 16 + er;
            float bc = bf1[q * 128 + colq];
            #pragma unroll
            for (int r = 0; r < 4; ++r) {
                int rl2 = wave * 16 + kg * 4 + r;
                float hv = gelu_exact(acch[f][r] + bc);
                int byte = rl2 * 256 + ((colq * 2) ^ ((rl2 & 7) << 4));
                *reinterpret_cast<ushort*>(reinterpret_cast<char*>(Hb) + byte) = bfbits(hv);
            }
        }
        __builtin_amdgcn_wave_barrier();
        bf16x8_t afH[4];
        #pragma unroll
        for (int ks = 0; ks < 4; ++ks)
            afH[ks] = *reinterpret_cast<const bf16x8_t*>(
                reinterpret_cast<char*>(Hb) + lrow * 256 + ((ks * 64 + kg * 16) ^ rsw));
        // ---- FFN2 partial (stages 2+q*4+2, +3) ----
        #pragma unroll
        for (int hh = 0; hh < 2; ++hh) {
            __syncthreads();
            stage_write(WsB, wreg, tid);
            {
                int ns = 2 + q * 4 + 2 + hh + 1, strd;
                if (ns < 18) {
                    const ushort* p = wf_stage_ptr(ns, woT, w1t, w2t, &strd);
                    stage_load(p, strd, wreg, tid);
                }
            }
            __syncthreads();
            #pragma unroll
            for (int ks2 = 0; ks2 < 4; ++ks2) {
                #pragma unroll
                for (int fl = 0; fl < 4; ++fl) {
                    int fc = fl * 16 + er;
                    bf16x8_t bfr = *reinterpret_cast<const bf16x8_t*>(
                        WsB + fc * 256 + ((ks2 * 64 + kg * 16) ^ ((fc & 7) << 4)));
                    acc2[hh * 4 + fl] = __builtin_amdgcn_mfma_f32_16x16x32_bf16(afH[ks2], bfr, acc2[hh * 4 + fl], 0, 0, 0);
                }
            }
        }
    }
    // epilogue
    #pragma unroll
    for (int f = 0; f < 8; ++f) {
        int col = (f >> 2) * 64 + (f & 3) * 16 + er;
        float bc = bf2[col];
        #pragma unroll
        for (int r = 0; r < 4; ++r) {
            int row = row0 + kg * 4 + r;
            if (row < M) out[(size_t)row * 128 + col] = acc2[f][r] + bc + acc[f][r];
        }
    }
}

// ---------------- Single-kernel scan (last-block aggregation; proven in R12) ----------------
#define SCAN_BLOCKS ((NNODES + 255) / 256)   // 196
__global__ void scan_kernel(const int* __restrict__ counts, int* __restrict__ rowstart,
                            int* __restrict__ blocksum, int* __restrict__ blockoff,
                            int* __restrict__ done_ctr) {
    __shared__ int sh[256];
    __shared__ int isLast;
    int t = threadIdx.x, i = blockIdx.x * 256 + t;
    int c = (i < NNODES) ? counts[i] : 0;
    sh[t] = c; __syncthreads();
    int v = c;
    #pragma unroll
    for (int off = 1; off < 256; off <<= 1) {
        int u = (t >= off) ? sh[t - off] : 0;
        __syncthreads();
        v += u; sh[t] = v;
        __syncthreads();
    }
    if (i < NNODES) rowstart[i] = v - c;
    if (t == 255) blocksum[blockIdx.x] = v;
    __threadfence();
    if (t == 0) isLast = (atomicAdd(done_ctr, 1) == gridDim.x - 1);
    __syncthreads();
    if (!isLast) return;
    volatile const int* bs = blocksum;
    int c2 = (t < SCAN_BLOCKS) ? bs[t] : 0;
    __syncthreads();
    sh[t] = c2; __syncthreads();
    int v2 = c2;
    #pragma unroll
    for (int off = 1; off < 256; off <<= 1) {
        int u = (t >= off) ? sh[t - off] : 0;
        __syncthreads();
        v2 += u; sh[t] = v2;
        __syncthreads();
    }
    if (t < SCAN_BLOCKS) blockoff[t] = v2 - c2;
}

// ---------------- Edge bias + CSR scatter (grid-stride, reg double-buffered stream) ----------------
#define EB_TILES (NEDGES / 64)   // 12500
__global__ __launch_bounds__(256)
void edge_bias_scatter(const float* __restrict__ EA, const ushort* __restrict__ wet,
                       const float* __restrict__ be, const int* __restrict__ ei,
                       const int* __restrict__ rowstart, const int* __restrict__ blockoff,
                       const int* __restrict__ rank,
                       ushort* __restrict__ ebs_sorted, int* __restrict__ col_sorted) {
    __shared__ ushort lds[64 * 128];
    int tid = threadIdx.x, lane = tid & 63, wave = tid >> 6;
    int er = lane & 15, kg = lane >> 4;
    int lrow = wave * 16 + er;
    float beh = be[er & 7];
    int stride = gridDim.x;
    int tile = blockIdx.x;
    float4 r[8];
    if (tile < EB_TILES) {
        const float4* src = reinterpret_cast<const float4*>(EA + (size_t)tile * 64 * 128);
        #pragma unroll
        for (int it = 0; it < 8; ++it) r[it] = src[it * 256 + tid];
    }
    for (; tile < EB_TILES; tile += stride) {
        #pragma unroll
        for (int it = 0; it < 8; ++it) {
            int idx = it * 256 + tid;
            int elem = idx * 4;
            int row = elem >> 7, col = elem & 127;
            uint2 pk;
            pk.x = pack2(r[it].x, r[it].y);
            pk.y = pack2(r[it].z, r[it].w);
            int byte = row * 256 + ((col * 2) ^ ((row & 7) << 4));
            *reinterpret_cast<uint2*>(reinterpret_cast<char*>(lds) + byte) = pk;
        }
        __syncthreads();
        int ntile = tile + stride;
        if (ntile < EB_TILES) {
            const float4* src = reinterpret_cast<const float4*>(EA + (size_t)ntile * 64 * 128);
            #pragma unroll
            for (int it = 0; it < 8; ++it) r[it] = src[it * 256 + tid];
        }
        f32x4_t acc = (f32x4_t){0.f, 0.f, 0.f, 0.f};
        #pragma unroll
        for (int ks = 0; ks < 4; ++ks) {
            int cb = (ks * 64 + kg * 16) ^ ((er & 7) << 4);
            bf16x8_t af = *reinterpret_cast<const bf16x8_t*>(
                reinterpret_cast<char*>(lds) + lrow * 256 + cb);
            bf16x8_t bfr = *reinterpret_cast<const bf16x8_t*>(wet + er * 128 + ks * 32 + kg * 8);
            acc = __builtin_amdgcn_mfma_f32_16x16x32_bf16(af, bfr, acc, 0, 0, 0);
        }
        int e0 = tile * 64 + wave * 16;
        int pos = 0;
        if (lane < 16) {
            int e = e0 + lane;
            int row = ei[e], col = ei[NEDGES + e];
            pos = rowstart[row] + blockoff[row >> 8] + rank[e];
            col_sorted[pos] = col;
        }
        #pragma unroll
        for (int rr = 0; rr < 4; ++rr) {
            int pj = __shfl(pos, kg * 4 + rr, 64);
            if (er < 8) ebs_sorted[(size_t)pj * 8 + er] = bfbits(acc[rr] + beh);
        }
        __syncthreads();
    }
}

// ---------------- Fused attention: 8-deep batched prefetch flash aggregation ----------------
__global__ __launch_bounds__(256)
void attn_node_kernel(const int* __restrict__ rowstart, const int* __restrict__ blockoff,
                      const int* __restrict__ col_sorted,
                      const ushort* __restrict__ ebs_sorted, const ushort* __restrict__ Qb,
                      const uint* __restrict__ KVp, ushort* __restrict__ agg) {
    int wave = threadIdx.x >> 6;
    int lane = threadIdx.x & 63;
    int n = blockIdx.x * 4 + wave;
    if (n >= NNODES) return;
    int s0 = rowstart[n] + blockoff[n >> 8];
    int s1 = (n + 1 == NNODES) ? NEDGES : rowstart[n + 1] + blockoff[(n + 1) >> 8];
    int h = lane >> 3;

    uint qu = *reinterpret_cast<const uint*>(Qb + (size_t)n * 128 + lane * 2);
    float q0 = lo16(qu), q1 = hi16(qu);

    float m = NEG_SENTINEL, ssum = 0.f, a0 = 0.f, a1 = 0.f;
    int p = s0;
    for (; p + 8 <= s1; p += 8) {
        int cc[8]; uint2 kv[8]; float ebv[8], dd[8];
        #pragma unroll
        for (int i = 0; i < 8; ++i) cc[i] = col_sorted[p + i];
        #pragma unroll
        for (int i = 0; i < 8; ++i)
            kv[i] = *reinterpret_cast<const uint2*>(KVp + (size_t)cc[i] * 128 + lane * 2);
        #pragma unroll
        for (int i = 0; i < 8; ++i) ebv[i] = b2f(ebs_sorted[(size_t)(p + i) * 8 + h]);
        #pragma unroll
        for (int i = 0; i < 8; ++i) {
            float d = q0 * lo16(kv[i].x) + q1 * lo16(kv[i].y);
            d += __shfl_xor(d, 1, 64);
            d += __shfl_xor(d, 2, 64);
            d += __shfl_xor(d, 4, 64);
            dd[i] = d * 0.25f + ebv[i];
        }
        float mx = m;
        #pragma unroll
        for (int i = 0; i < 8; ++i) mx = fmaxf(mx, dd[i]);
        float sc = __expf(m - mx);
        float pv[8];
        #pragma unroll
        for (int i = 0; i < 8; ++i) pv[i] = __expf(dd[i] - mx);
        float psum = ((pv[0] + pv[1]) + (pv[2] + pv[3])) + ((pv[4] + pv[5]) + (pv[6] + pv[7]));
        float v0 = 0.f, v1 = 0.f;
        #pragma unroll
        for (int i = 0; i < 8; ++i) {
            v0 += pv[i] * hi16(kv[i].x);
            v1 += pv[i] * hi16(kv[i].y);
        }
        ssum = ssum * sc + psum;
        a0 = a0 * sc + v0;
        a1 = a1 * sc + v1;
        m = mx;
    }
    for (; p + 4 <= s1; p += 4) {
        int cc[4]; uint2 kv[4]; float ebv[4], dd[4];
        #pragma unroll
        for (int i = 0; i < 4; ++i) cc[i] = col_sorted[p + i];
        #pragma unroll
        for (int i = 0; i < 4; ++i)
            kv[i] = *reinterpret_cast<const uint2*>(KVp + (size_t)cc[i] * 128 + lane * 2);
        #pragma unroll
        for (int i = 0; i < 4; ++i) ebv[i] = b2f(ebs_sorted[(size_t)(p + i) * 8 + h]);
        #pragma unroll
        for (int i = 0; i < 4; ++i) {
            float d = q0 * lo16(kv[i].x) + q1 * lo16(kv[i].y);
            d += __shfl_xor(d, 1, 64);
            d += __shfl_xor(d, 2, 64);
            d += __shfl_xor(d, 4, 64);
            dd[i] = d * 0.25f + ebv[i];
        }
        float mx = fmaxf(fmaxf(fmaxf(dd[0], dd[1]), fmaxf(dd[2], dd[3])), m);
        float sc = __expf(m - mx);
        float p0 = __expf(dd[0] - mx), p1 = __expf(dd[1] - mx);
        float p2 = __expf(dd[2] - mx), p3 = __expf(dd[3] - mx);
        ssum = ssum * sc + ((p0 + p1) + (p2 + p3));
        a0 = a0 * sc + p0 * hi16(kv[0].x) + p1 * hi16(kv[1].x) + p2 * hi16(kv[2].x) + p3 * hi16(kv[3].x);
        a1 = a1 * sc + p0 * hi16(kv[0].y) + p1 * hi16(kv[1].y) + p2 * hi16(kv[2].y) + p3 * hi16(kv[3].y);
        m = mx;
    }
    for (; p < s1; ++p) {
        int c = col_sorted[p];
        uint2 kv = *reinterpret_cast<const uint2*>(KVp + (size_t)c * 128 + lane * 2);
        float eb = b2f(ebs_sorted[(size_t)p * 8 + h]);
        float d = q0 * lo16(kv.x) + q1 * lo16(kv.y);
        d += __shfl_xor(d, 1, 64);
        d += __shfl_xor(d, 2, 64);
        d += __shfl_xor(d, 4, 64);
        float s = d * 0.25f + eb;
        float mn = fmaxf(m, s);
        float sc = __expf(m - mn);
        float pv = __expf(s - mn);
        ssum = ssum * sc + pv;
        a0 = a0 * sc + pv * hi16(kv.x);
        a1 = a1 * sc + pv * hi16(kv.y);
        m = mn;
    }
    float inv = (ssum > 0.f) ? 1.0f / ssum : 0.f;
    reinterpret_cast<uint*>(agg + (size_t)n * 128)[lane] = pack2(a0 * inv, a1 * inv);
}

extern "C" void kernel_launch(void* const* d_in, const int* in_sizes, int n_in,
                              void* d_out, int out_size, void* d_ws, size_t ws_size,
                              hipStream_t stream) {
    const float* x   = (const float*)d_in[0];
    const int*   ei  = (const int*)d_in[1];
    const float* ea  = (const float*)d_in[2];
    const float* Wq  = (const float*)d_in[3];  const float* bq  = (const float*)d_in[4];
    const float* Wk  = (const float*)d_in[5];  const float* bk  = (const float*)d_in[6];
    const float* Wv  = (const float*)d_in[7];  const float* bv  = (const float*)d_in[8];
    const float* Wo  = (const float*)d_in[9];  const float* bo  = (const float*)d_in[10];
    const float* We  = (const float*)d_in[11]; const float* be  = (const float*)d_in[12];
    const float* W1  = (const float*)d_in[13]; const float* bf1 = (const float*)d_in[14];
    const float* W2  = (const float*)d_in[15]; const float* bf2 = (const float*)d_in[16];
    const float* g1  = (const float*)d_in[17]; const float* b1  = (const float*)d_in[18];
    const float* g2  = (const float*)d_in[19]; const float* b2  = (const float*)d_in[20];

    char* base = (char*)d_ws;
    ushort* agg       = (ushort*)(base);               // bf16 [N,128] = 12.8 MB
    ushort* Qb        = (ushort*)(base + 12800000);    // bf16 [N,128] = 12.8 MB
    uint*   KVp       = (uint*)(base + 25600000);      // uint [N,128] = 25.6 MB (K lo | V hi)
    ushort* ebs_sorted= (ushort*)(base + 51200000);    // bf16 [E,8] = 12.8 MB (CSR order)
    int*    col_sorted= (int*)(base + 64000000);       // [E] = 3.2 MB
    int*    rank      = (int*)(base + 67200000);       // [E] = 3.2 MB
    int*    counts    = (int*)(base + 70400000);       // [N] (+ done_ctr)
    int*    done_ctr  = counts + NNODES;               // [1]
    int*    rowstart  = (int*)(base + 70600004);       // [N]
    ushort* wt4       = (ushort*)(base + 70800016);    // [512][128] (Wq|Wk|Wv|Wo)^T
    ushort* w1t       = (ushort*)(base + 70931088);    // [512][128]
    ushort* w2t       = (ushort*)(base + 71062160);    // [128][512]
    ushort* wet       = (ushort*)(base + 71193232);    // [16][128]
    float*  b384      = (float*)(base + 71197328);     // [384]
    int*    blocksum  = (int*)(base + 71198864);       // [196]
    int*    blockoff  = (int*)(base + 71199648);       // [196]
    // peak ~71.2 MB

    zero_counts<<<(NNODES + 256) / 256, 256, 0, stream>>>(counts);

    setup_kernel<<<NEDGES / 256 + 778, 256, 0, stream>>>(ei, counts, rank, Wq, Wk, Wv, Wo,
                                                         W1, W2, We, bq, bk, bv,
                                                         wt4, w1t, w2t, wet, b384);

    dim3 g128((NNODES + 63) / 64, 1);
    ln_qkv_kernel<<<g128, 256, 0, stream>>>(x, g1, b1, wt4, b384, Qb, KVp, NNODES);

    scan_kernel<<<SCAN_BLOCKS, 256, 0, stream>>>(counts, rowstart, blocksum, blockoff, done_ctr);

    edge_bias_scatter<<<2048, 256, 0, stream>>>(ea, wet, be, ei, rowstart, blockoff, rank,
                                                ebs_sorted, col_sorted);
    attn_node_kernel<<<(NNODES + 3) / 4, 256, 0, stream>>>(rowstart, blockoff, col_sorted,
                                                           ebs_sorted, Qb, KVp, agg);

    wo_ffn_kernel<<<g128, 256, 0, stream>>>(agg, wt4 + 49152, bo, x, g2, b2,
                                            w1t, bf1, w2t, bf2, (float*)d_out, NNODES);
}

// Round 24
// 330.135 us; speedup vs baseline: 1.2298x; 1.2298x over previous
//
#include <hip/hip_runtime.h>
#include <hip/hip_bf16.h>
#include <math.h>

#define NNODES 50000
#define NEDGES 800000
#define DIM 128
#define NH 8

#define NEG_SENTINEL -3.0e38f

typedef __attribute__((ext_vector_type(8))) short bf16x8_t;
typedef __attribute__((ext_vector_type(4))) float f32x4_t;

__device__ __forceinline__ float gelu_exact(float v) {
    return 0.5f * v * (1.0f + erff(v * 0.70710678118654752f));
}
__device__ __forceinline__ ushort bfbits(float f) {
    uint u = __float_as_uint(f);
    u += 0x7fffu + ((u >> 16) & 1u);
    return (ushort)(u >> 16);
}
__device__ __forceinline__ uint pack2(float a, float b) {
    return (uint)bfbits(a) | ((uint)bfbits(b) << 16);
}
__device__ __forceinline__ float lo16(uint u) { return __uint_as_float(u << 16); }
__device__ __forceinline__ float hi16(uint u) { return __uint_as_float(u & 0xffff0000u); }
__device__ __forceinline__ float b2f(ushort u) { return __uint_as_float(((uint)u) << 16); }

// ---------------- zero counts ----------------
__global__ void zero_counts(int* __restrict__ counts) {
    int i = blockIdx.x * 256 + threadIdx.x;
    if (i < NNODES) counts[i] = 0;
}

// ---------------- setup: edge histogram (+rank) + weight transpose/convert + bias pack ----------------
__global__ void setup_kernel(const int* __restrict__ ei, int* __restrict__ counts,
                             int* __restrict__ rank,
                             const float* __restrict__ Wq, const float* __restrict__ Wk,
                             const float* __restrict__ Wv, const float* __restrict__ Wo,
                             const float* __restrict__ W1, const float* __restrict__ W2,
                             const float* __restrict__ We,
                             const float* __restrict__ bq, const float* __restrict__ bk,
                             const float* __restrict__ bv,
                             ushort* __restrict__ wt4, ushort* __restrict__ w1t,
                             ushort* __restrict__ w2t, ushort* __restrict__ wet,
                             float* __restrict__ b384) {
    int b = blockIdx.x;
    if (b < NEDGES / 256) {
        int e = b * 256 + threadIdx.x;
        rank[e] = atomicAdd(&counts[ei[e]], 1);   // rank within row (order arbitrary)
        return;
    }
    int i = (b - NEDGES / 256) * 256 + threadIdx.x;
    if (i < 65536) {
        int w = i >> 14, j = i & 16383;
        int c = j >> 7, k = j & 127;
        const float* src = (w == 0) ? Wq : (w == 1) ? Wk : (w == 2) ? Wv : Wo;
        wt4[i] = bfbits(src[k * 128 + c]);
    } else if (i < 131072) {
        int j = i - 65536;
        int c = j >> 7, k = j & 127;
        w1t[j] = bfbits(W1[k * 512 + c]);
    } else if (i < 196608) {
        int j = i - 131072;
        int c = j >> 9, k = j & 511;
        w2t[j] = bfbits(W2[k * 128 + c]);
    } else if (i < 198656) {
        int j = i - 196608;
        int h = j >> 7, k = j & 127;
        wet[j] = (h < 8) ? bfbits(We[k * 8 + h]) : (ushort)0;
    } else if (i < 198656 + 384) {
        int j = i - 198656;
        b384[j] = (j < 128) ? bq[j] : (j < 256) ? bk[j - 128] : bv[j - 256];
    }
}

// ---------------- Fused LN1 + QKV GEMM with LDS weight staging ----------------
// Ws: 16KB stage = 64 weight-cols x 128 k, XOR-swizzled. 6 stages cover 384 cols.
__global__ __launch_bounds__(256)
void ln_qkv_kernel(const float* __restrict__ x, const float* __restrict__ g1,
                   const float* __restrict__ b1, const ushort* __restrict__ wt4,
                   const float* __restrict__ b384, ushort* __restrict__ Qb,
                   uint* __restrict__ KVp, int M) {
    __shared__ ushort An[64 * 128];   // swizzled bf16 xn tile; rows wave*16.. wave-private
    __shared__ ushort Ws[64 * 128];   // shared weight stage (16KB)
    int tid = threadIdx.x, lane = tid & 63, wave = tid >> 6;
    int row0b = blockIdx.x * 64;
    int sr = lane >> 4;
    int sl = lane & 15;
    char* WsB = reinterpret_cast<char*>(Ws);
    float4 ga = reinterpret_cast<const float4*>(g1)[sl * 2];
    float4 gb = reinterpret_cast<const float4*>(g1)[sl * 2 + 1];
    float4 ba = reinterpret_cast<const float4*>(b1)[sl * 2];
    float4 bbv = reinterpret_cast<const float4*>(b1)[sl * 2 + 1];
    #pragma unroll
    for (int g = 0; g < 4; ++g) {
        int rl = wave * 16 + g * 4 + sr;
        int srow = min(row0b + rl, M - 1);
        const float4* xp = reinterpret_cast<const float4*>(x + (size_t)srow * 128 + sl * 8);
        float4 a = xp[0], b = xp[1];
        float s  = ((a.x + a.y) + (a.z + a.w)) + ((b.x + b.y) + (b.z + b.w));
        float sq = ((a.x*a.x + a.y*a.y) + (a.z*a.z + a.w*a.w)) +
                   ((b.x*b.x + b.y*b.y) + (b.z*b.z + b.w*b.w));
        #pragma unroll
        for (int mm = 1; mm < 16; mm <<= 1) {
            s  += __shfl_xor(s, mm, 64);
            sq += __shfl_xor(sq, mm, 64);
        }
        float mean = s * (1.0f / DIM);
        float var  = sq * (1.0f / DIM) - mean * mean;
        float rs = rsqrtf(var + 1e-5f);
        uint4 pk;
        pk.x = pack2((a.x - mean) * rs * ga.x + ba.x, (a.y - mean) * rs * ga.y + ba.y);
        pk.y = pack2((a.z - mean) * rs * ga.z + ba.z, (a.w - mean) * rs * ga.w + ba.w);
        pk.z = pack2((b.x - mean) * rs * gb.x + bbv.x, (b.y - mean) * rs * gb.y + bbv.y);
        pk.w = pack2((b.z - mean) * rs * gb.z + bbv.z, (b.w - mean) * rs * gb.w + bbv.w);
        int byte = rl * 256 + ((sl * 16) ^ ((rl & 7) << 4));
        *reinterpret_cast<uint4*>(reinterpret_cast<char*>(An) + byte) = pk;
    }
    __builtin_amdgcn_wave_barrier();
    int er = lane & 15, kg = lane >> 4;
    int lrow = wave * 16 + er;
    int rsw = (er & 7) << 4;
    // preload An fragments (reused across all 6 weight stages)
    bf16x8_t afN[4];
    #pragma unroll
    for (int ks = 0; ks < 4; ++ks)
        afN[ks] = *reinterpret_cast<const bf16x8_t*>(
            reinterpret_cast<char*>(An) + lrow * 256 + ((ks * 64 + kg * 16) ^ rsw));
    f32x4_t acc[24];
    #pragma unroll
    for (int f = 0; f < 24; ++f) acc[f] = (f32x4_t){0.f, 0.f, 0.f, 0.f};
    // 6 stages of 64 weight columns
    #pragma unroll
    for (int st = 0; st < 6; ++st) {
        __syncthreads();
        #pragma unroll
        for (int it = 0; it < 4; ++it) {
            int idx = it * 256 + tid;            // 1024 chunks of 16B
            int col = idx >> 4, ch = idx & 15;
            uint4 d = *reinterpret_cast<const uint4*>(wt4 + (size_t)(st * 64 + col) * 128 + ch * 8);
            *reinterpret_cast<uint4*>(WsB + col * 256 + ((ch * 16) ^ ((col & 7) << 4))) = d;
        }
        __syncthreads();
        #pragma unroll
        for (int ks = 0; ks < 4; ++ks) {
            #pragma unroll
            for (int fl = 0; fl < 4; ++fl) {
                int fc = fl * 16 + er;
                bf16x8_t bfr = *reinterpret_cast<const bf16x8_t*>(
                    WsB + fc * 256 + ((ks * 64 + kg * 16) ^ ((fc & 7) << 4)));
                acc[st * 4 + fl] = __builtin_amdgcn_mfma_f32_16x16x32_bf16(afN[ks], bfr, acc[st * 4 + fl], 0, 0, 0);
            }
        }
    }
    // epilogue: f = st*4+fl -> col = (f>>2)*64 + (f&3)*16 + er
    #pragma unroll
    for (int f = 0; f < 24; ++f) {
        int col = (f >> 2) * 64 + (f & 3) * 16 + er;
        float bc = b384[col];
        #pragma unroll
        for (int r = 0; r < 4; ++r) {
            int row = row0b + wave * 16 + kg * 4 + r;
            if (row < M) {
                float v = acc[f][r] + bc;
                if (col < 128) {
                    Qb[(size_t)row * 128 + col] = bfbits(v);
                } else if (col < 256) {
                    reinterpret_cast<ushort*>(KVp + (size_t)row * 128 + (col - 128))[0] = bfbits(v);
                } else {
                    reinterpret_cast<ushort*>(KVp + (size_t)row * 128 + (col - 256))[1] = bfbits(v);
                }
            }
        }
    }
}

// ---------------- Wo + residual + LN2 + FFN with LDS weight staging ----------------
__global__ __launch_bounds__(256)
void wo_ffn_kernel(const ushort* __restrict__ A, const ushort* __restrict__ woT,
                   const float* __restrict__ bo, const float* __restrict__ xres,
                   const float* __restrict__ g2, const float* __restrict__ b2,
                   const ushort* __restrict__ w1t, const float* __restrict__ bf1,
                   const ushort* __restrict__ w2t, const float* __restrict__ bf2,
                   float* __restrict__ out, int M) {
    __shared__ ushort An[64 * 128];   // wave-private rows
    __shared__ ushort Hb[64 * 128];   // wave-private rows
    __shared__ ushort Ws[64 * 128];   // shared weight stage (16KB)
    int tid = threadIdx.x, lane = tid & 63, wave = tid >> 6;
    int row0 = blockIdx.x * 64 + wave * 16;
    int er = lane & 15, kg = lane >> 4;
    int arow = min(row0 + er, M - 1);
    char* WsB = reinterpret_cast<char*>(Ws);

    // ---- Phase A: Wo GEMM (2 staged halves of Wo^T) ----
    f32x4_t acc[8];
    #pragma unroll
    for (int f = 0; f < 8; ++f) acc[f] = (f32x4_t){0.f, 0.f, 0.f, 0.f};
    bf16x8_t afA[4];
    #pragma unroll
    for (int ks = 0; ks < 4; ++ks)
        afA[ks] = *reinterpret_cast<const bf16x8_t*>(A + (size_t)arow * 128 + ks * 32 + kg * 8);
    #pragma unroll
    for (int hh = 0; hh < 2; ++hh) {
        __syncthreads();
        #pragma unroll
        for (int it = 0; it < 4; ++it) {
            int idx = it * 256 + tid;
            int col = idx >> 4, ch = idx & 15;
            uint4 d = *reinterpret_cast<const uint4*>(woT + (size_t)(hh * 64 + col) * 128 + ch * 8);
            *reinterpret_cast<uint4*>(WsB + col * 256 + ((ch * 16) ^ ((col & 7) << 4))) = d;
        }
        __syncthreads();
        #pragma unroll
        for (int ks = 0; ks < 4; ++ks) {
            #pragma unroll
            for (int fl = 0; fl < 4; ++fl) {
                int fc = fl * 16 + er;
                bf16x8_t bfr = *reinterpret_cast<const bf16x8_t*>(
                    WsB + fc * 256 + ((ks * 64 + kg * 16) ^ ((fc & 7) << 4)));
                acc[hh * 4 + fl] = __builtin_amdgcn_mfma_f32_16x16x32_bf16(afA[ks], bfr, acc[hh * 4 + fl], 0, 0, 0);
            }
        }
    }
    // + bo + residual;  acc f=hh*4+fl -> col = hh*64+fl*16+er
    float g2l[8], b2l[8];
    #pragma unroll
    for (int f = 0; f < 8; ++f) {
        int col = (f >> 2) * 64 + (f & 3) * 16 + er;
        float bc = bo[col];
        g2l[f] = g2[col]; b2l[f] = b2[col];
        #pragma unroll
        for (int r = 0; r < 4; ++r) {
            int row = min(row0 + kg * 4 + r, M - 1);
            acc[f][r] += bc + xres[(size_t)row * 128 + col];
        }
    }
    // LN2 -> An (wave-private)
    #pragma unroll
    for (int r = 0; r < 4; ++r) {
        float s = 0.f, sq = 0.f;
        #pragma unroll
        for (int f = 0; f < 8; ++f) { s += acc[f][r]; sq += acc[f][r] * acc[f][r]; }
        #pragma unroll
        for (int m = 1; m < 16; m <<= 1) {
            s  += __shfl_xor(s, m, 64);
            sq += __shfl_xor(sq, m, 64);
        }
        float mean = s * (1.0f / DIM);
        float var  = sq * (1.0f / DIM) - mean * mean;
        float rs = rsqrtf(var + 1e-5f);
        int rl = wave * 16 + kg * 4 + r;
        #pragma unroll
        for (int f = 0; f < 8; ++f) {
            int col = (f >> 2) * 64 + (f & 3) * 16 + er;
            float xv = (acc[f][r] - mean) * rs * g2l[f] + b2l[f];
            int byte = rl * 256 + ((col * 2) ^ ((rl & 7) << 4));
            *reinterpret_cast<ushort*>(reinterpret_cast<char*>(An) + byte) = bfbits(xv);
        }
    }
    __builtin_amdgcn_wave_barrier();

    int lrow = wave * 16 + er;
    int rsw = (lrow & 7) << 4;
    f32x4_t acc2[8];
    #pragma unroll
    for (int f = 0; f < 8; ++f) acc2[f] = (f32x4_t){0.f, 0.f, 0.f, 0.f};

    bf16x8_t afN[4];
    #pragma unroll
    for (int ks = 0; ks < 4; ++ks)
        afN[ks] = *reinterpret_cast<const bf16x8_t*>(
            reinterpret_cast<char*>(An) + lrow * 256 + ((ks * 64 + kg * 16) ^ rsw));

    for (int q = 0; q < 4; ++q) {
        // ---- FFN1 quarter q in 2 staged halves ----
        f32x4_t acch[8];
        #pragma unroll
        for (int f = 0; f < 8; ++f) acch[f] = (f32x4_t){0.f, 0.f, 0.f, 0.f};
        #pragma unroll
        for (int hh = 0; hh < 2; ++hh) {
            __syncthreads();
            #pragma unroll
            for (int it = 0; it < 4; ++it) {
                int idx = it * 256 + tid;
                int col = idx >> 4, ch = idx & 15;
                uint4 d = *reinterpret_cast<const uint4*>(
                    w1t + (size_t)(q * 128 + hh * 64 + col) * 128 + ch * 8);
                *reinterpret_cast<uint4*>(WsB + col * 256 + ((ch * 16) ^ ((col & 7) << 4))) = d;
            }
            __syncthreads();
            #pragma unroll
            for (int ks = 0; ks < 4; ++ks) {
                #pragma unroll
                for (int fl = 0; fl < 4; ++fl) {
                    int fc = fl * 16 + er;
                    bf16x8_t bfr = *reinterpret_cast<const bf16x8_t*>(
                        WsB + fc * 256 + ((ks * 64 + kg * 16) ^ ((fc & 7) << 4)));
                    acch[hh * 4 + fl] = __builtin_amdgcn_mfma_f32_16x16x32_bf16(afN[ks], bfr, acch[hh * 4 + fl], 0, 0, 0);
                }
            }
        }
        // gelu -> Hb
        #pragma unroll
        for (int f = 0; f < 8; ++f) {
            int colq = (f >> 2) * 64 + (f & 3) * 16 + er;
            float bc = bf1[q * 128 + colq];
            #pragma unroll
            for (int r = 0; r < 4; ++r) {
                int rl2 = wave * 16 + kg * 4 + r;
                float hv = gelu_exact(acch[f][r] + bc);
                int byte = rl2 * 256 + ((colq * 2) ^ ((rl2 & 7) << 4));
                *reinterpret_cast<ushort*>(reinterpret_cast<char*>(Hb) + byte) = bfbits(hv);
            }
        }
        __builtin_amdgcn_wave_barrier();
        bf16x8_t afH[4];
        #pragma unroll
        for (int ks = 0; ks < 4; ++ks)
            afH[ks] = *reinterpret_cast<const bf16x8_t*>(
                reinterpret_cast<char*>(Hb) + lrow * 256 + ((ks * 64 + kg * 16) ^ rsw));
        // ---- FFN2 partial in 2 staged halves ----
        #pragma unroll
        for (int hh = 0; hh < 2; ++hh) {
            __syncthreads();
            #pragma unroll
            for (int it = 0; it < 4; ++it) {
                int idx = it * 256 + tid;
                int col = idx >> 4, ch = idx & 15;
                uint4 d = *reinterpret_cast<const uint4*>(
                    w2t + (size_t)(hh * 64 + col) * 512 + q * 128 + ch * 8);
                *reinterpret_cast<uint4*>(WsB + col * 256 + ((ch * 16) ^ ((col & 7) << 4))) = d;
            }
            __syncthreads();
            #pragma unroll
            for (int ks2 = 0; ks2 < 4; ++ks2) {
                #pragma unroll
                for (int fl = 0; fl < 4; ++fl) {
                    int fc = fl * 16 + er;
                    bf16x8_t bfr = *reinterpret_cast<const bf16x8_t*>(
                        WsB + fc * 256 + ((ks2 * 64 + kg * 16) ^ ((fc & 7) << 4)));
                    acc2[hh * 4 + fl] = __builtin_amdgcn_mfma_f32_16x16x32_bf16(afH[ks2], bfr, acc2[hh * 4 + fl], 0, 0, 0);
                }
            }
        }
    }
    // epilogue
    #pragma unroll
    for (int f = 0; f < 8; ++f) {
        int col = (f >> 2) * 64 + (f & 3) * 16 + er;
        float bc = bf2[col];
        #pragma unroll
        for (int r = 0; r < 4; ++r) {
            int row = row0 + kg * 4 + r;
            if (row < M) out[(size_t)row * 128 + col] = acc2[f][r] + bc + acc[f][r];
        }
    }
}

// ---------------- 2-phase scan ----------------
#define SCAN_BLOCKS ((NNODES + 255) / 256)   // 196
__global__ void scan_ph1(const int* __restrict__ counts, int* __restrict__ rowstart,
                         int* __restrict__ blocksum) {
    __shared__ int sh[256];
    int t = threadIdx.x, i = blockIdx.x * 256 + t;
    int c = (i < NNODES) ? counts[i] : 0;
    sh[t] = c; __syncthreads();
    int v = c;
    #pragma unroll
    for (int off = 1; off < 256; off <<= 1) {
        int u = (t >= off) ? sh[t - off] : 0;
        __syncthreads();
        v += u; sh[t] = v;
        __syncthreads();
    }
    if (i < NNODES) rowstart[i] = v - c;
    if (t == 255) blocksum[blockIdx.x] = v;
}
__global__ void scan_ph2(const int* __restrict__ blocksum, int* __restrict__ blockoff) {
    __shared__ int sh[256];
    int t = threadIdx.x;
    int c = (t < SCAN_BLOCKS) ? blocksum[t] : 0;
    sh[t] = c; __syncthreads();
    int v = c;
    #pragma unroll
    for (int off = 1; off < 256; off <<= 1) {
        int u = (t >= off) ? sh[t - off] : 0;
        __syncthreads();
        v += u; sh[t] = v;
        __syncthreads();
    }
    if (t < SCAN_BLOCKS) blockoff[t] = v - c;
}

// ---------------- Edge bias + CSR scatter (grid-stride, reg double-buffered stream) ----------------
#define EB_TILES (NEDGES / 64)   // 12500
__global__ __launch_bounds__(256)
void edge_bias_scatter(const float* __restrict__ EA, const ushort* __restrict__ wet,
                       const float* __restrict__ be, const int* __restrict__ ei,
                       const int* __restrict__ rowstart, const int* __restrict__ blockoff,
                       const int* __restrict__ rank,
                       ushort* __restrict__ ebs_sorted, int* __restrict__ col_sorted) {
    __shared__ ushort lds[64 * 128];
    int tid = threadIdx.x, lane = tid & 63, wave = tid >> 6;
    int er = lane & 15, kg = lane >> 4;
    int lrow = wave * 16 + er;
    float beh = be[er & 7];
    int stride = gridDim.x;
    int tile = blockIdx.x;
    float4 r[8];
    if (tile < EB_TILES) {
        const float4* src = reinterpret_cast<const float4*>(EA + (size_t)tile * 64 * 128);
        #pragma unroll
        for (int it = 0; it < 8; ++it) r[it] = src[it * 256 + tid];
    }
    for (; tile < EB_TILES; tile += stride) {
        #pragma unroll
        for (int it = 0; it < 8; ++it) {
            int idx = it * 256 + tid;
            int elem = idx * 4;
            int row = elem >> 7, col = elem & 127;
            uint2 pk;
            pk.x = pack2(r[it].x, r[it].y);
            pk.y = pack2(r[it].z, r[it].w);
            int byte = row * 256 + ((col * 2) ^ ((row & 7) << 4));
            *reinterpret_cast<uint2*>(reinterpret_cast<char*>(lds) + byte) = pk;
        }
        __syncthreads();
        int ntile = tile + stride;
        if (ntile < EB_TILES) {
            const float4* src = reinterpret_cast<const float4*>(EA + (size_t)ntile * 64 * 128);
            #pragma unroll
            for (int it = 0; it < 8; ++it) r[it] = src[it * 256 + tid];
        }
        f32x4_t acc = (f32x4_t){0.f, 0.f, 0.f, 0.f};
        #pragma unroll
        for (int ks = 0; ks < 4; ++ks) {
            int cb = (ks * 64 + kg * 16) ^ ((er & 7) << 4);
            bf16x8_t af = *reinterpret_cast<const bf16x8_t*>(
                reinterpret_cast<char*>(lds) + lrow * 256 + cb);
            bf16x8_t bfr = *reinterpret_cast<const bf16x8_t*>(wet + er * 128 + ks * 32 + kg * 8);
            acc = __builtin_amdgcn_mfma_f32_16x16x32_bf16(af, bfr, acc, 0, 0, 0);
        }
        int e0 = tile * 64 + wave * 16;
        int pos = 0;
        if (lane < 16) {
            int e = e0 + lane;
            int row = ei[e], col = ei[NEDGES + e];
            pos = rowstart[row] + blockoff[row >> 8] + rank[e];
            col_sorted[pos] = col;
        }
        #pragma unroll
        for (int rr = 0; rr < 4; ++rr) {
            int pj = __shfl(pos, kg * 4 + rr, 64);
            if (er < 8) ebs_sorted[(size_t)pj * 8 + er] = bfbits(acc[rr] + beh);
        }
        __syncthreads();
    }
}

// ---------------- Fused attention: 8-deep batched prefetch flash aggregation ----------------
__global__ __launch_bounds__(256)
void attn_node_kernel(const int* __restrict__ rowstart, const int* __restrict__ blockoff,
                      const int* __restrict__ col_sorted,
                      const ushort* __restrict__ ebs_sorted, const ushort* __restrict__ Qb,
                      const uint* __restrict__ KVp, ushort* __restrict__ agg) {
    int wave = threadIdx.x >> 6;
    int lane = threadIdx.x & 63;
    int n = blockIdx.x * 4 + wave;
    if (n >= NNODES) return;
    int s0 = rowstart[n] + blockoff[n >> 8];
    int s1 = (n + 1 == NNODES) ? NEDGES : rowstart[n + 1] + blockoff[(n + 1) >> 8];
    int h = lane >> 3;

    uint qu = *reinterpret_cast<const uint*>(Qb + (size_t)n * 128 + lane * 2);
    float q0 = lo16(qu), q1 = hi16(qu);

    float m = NEG_SENTINEL, ssum = 0.f, a0 = 0.f, a1 = 0.f;
    int p = s0;
    for (; p + 8 <= s1; p += 8) {
        int cc[8]; uint2 kv[8]; float ebv[8], dd[8];
        #pragma unroll
        for (int i = 0; i < 8; ++i) cc[i] = col_sorted[p + i];
        #pragma unroll
        for (int i = 0; i < 8; ++i)
            kv[i] = *reinterpret_cast<const uint2*>(KVp + (size_t)cc[i] * 128 + lane * 2);
        #pragma unroll
        for (int i = 0; i < 8; ++i) ebv[i] = b2f(ebs_sorted[(size_t)(p + i) * 8 + h]);
        #pragma unroll
        for (int i = 0; i < 8; ++i) {
            float d = q0 * lo16(kv[i].x) + q1 * lo16(kv[i].y);
            d += __shfl_xor(d, 1, 64);
            d += __shfl_xor(d, 2, 64);
            d += __shfl_xor(d, 4, 64);
            dd[i] = d * 0.25f + ebv[i];
        }
        float mx = m;
        #pragma unroll
        for (int i = 0; i < 8; ++i) mx = fmaxf(mx, dd[i]);
        float sc = __expf(m - mx);
        float pv[8];
        #pragma unroll
        for (int i = 0; i < 8; ++i) pv[i] = __expf(dd[i] - mx);
        float psum = ((pv[0] + pv[1]) + (pv[2] + pv[3])) + ((pv[4] + pv[5]) + (pv[6] + pv[7]));
        float v0 = 0.f, v1 = 0.f;
        #pragma unroll
        for (int i = 0; i < 8; ++i) {
            v0 += pv[i] * hi16(kv[i].x);
            v1 += pv[i] * hi16(kv[i].y);
        }
        ssum = ssum * sc + psum;
        a0 = a0 * sc + v0;
        a1 = a1 * sc + v1;
        m = mx;
    }
    for (; p + 4 <= s1; p += 4) {
        int cc[4]; uint2 kv[4]; float ebv[4], dd[4];
        #pragma unroll
        for (int i = 0; i < 4; ++i) cc[i] = col_sorted[p + i];
        #pragma unroll
        for (int i = 0; i < 4; ++i)
            kv[i] = *reinterpret_cast<const uint2*>(KVp + (size_t)cc[i] * 128 + lane * 2);
        #pragma unroll
        for (int i = 0; i < 4; ++i) ebv[i] = b2f(ebs_sorted[(size_t)(p + i) * 8 + h]);
        #pragma unroll
        for (int i = 0; i < 4; ++i) {
            float d = q0 * lo16(kv[i].x) + q1 * lo16(kv[i].y);
            d += __shfl_xor(d, 1, 64);
            d += __shfl_xor(d, 2, 64);
            d += __shfl_xor(d, 4, 64);
            dd[i] = d * 0.25f + ebv[i];
        }
        float mx = fmaxf(fmaxf(fmaxf(dd[0], dd[1]), fmaxf(dd[2], dd[3])), m);
        float sc = __expf(m - mx);
        float p0 = __expf(dd[0] - mx), p1 = __expf(dd[1] - mx);
        float p2 = __expf(dd[2] - mx), p3 = __expf(dd[3] - mx);
        ssum = ssum * sc + ((p0 + p1) + (p2 + p3));
        a0 = a0 * sc + p0 * hi16(kv[0].x) + p1 * hi16(kv[1].x) + p2 * hi16(kv[2].x) + p3 * hi16(kv[3].x);
        a1 = a1 * sc + p0 * hi16(kv[0].y) + p1 * hi16(kv[1].y) + p2 * hi16(kv[2].y) + p3 * hi16(kv[3].y);
        m = mx;
    }
    for (; p < s1; ++p) {
        int c = col_sorted[p];
        uint2 kv = *reinterpret_cast<const uint2*>(KVp + (size_t)c * 128 + lane * 2);
        float eb = b2f(ebs_sorted[(size_t)p * 8 + h]);
        float d = q0 * lo16(kv.x) + q1 * lo16(kv.y);
        d += __shfl_xor(d, 1, 64);
        d += __shfl_xor(d, 2, 64);
        d += __shfl_xor(d, 4, 64);
        float s = d * 0.25f + eb;
        float mn = fmaxf(m, s);
        float sc = __expf(m - mn);
        float pv = __expf(s - mn);
        ssum = ssum * sc + pv;
        a0 = a0 * sc + pv * hi16(kv.x);
        a1 = a1 * sc + pv * hi16(kv.y);
        m = mn;
    }
    float inv = (ssum > 0.f) ? 1.0f / ssum : 0.f;
    reinterpret_cast<uint*>(agg + (size_t)n * 128)[lane] = pack2(a0 * inv, a1 * inv);
}

extern "C" void kernel_launch(void* const* d_in, const int* in_sizes, int n_in,
                              void* d_out, int out_size, void* d_ws, size_t ws_size,
                              hipStream_t stream) {
    const float* x   = (const float*)d_in[0];
    const int*   ei  = (const int*)d_in[1];
    const float* ea  = (const float*)d_in[2];
    const float* Wq  = (const float*)d_in[3];  const float* bq  = (const float*)d_in[4];
    const float* Wk  = (const float*)d_in[5];  const float* bk  = (const float*)d_in[6];
    const float* Wv  = (const float*)d_in[7];  const float* bv  = (const float*)d_in[8];
    const float* Wo  = (const float*)d_in[9];  const float* bo  = (const float*)d_in[10];
    const float* We  = (const float*)d_in[11]; const float* be  = (const float*)d_in[12];
    const float* W1  = (const float*)d_in[13]; const float* bf1 = (const float*)d_in[14];
    const float* W2  = (const float*)d_in[15]; const float* bf2 = (const float*)d_in[16];
    const float* g1  = (const float*)d_in[17]; const float* b1  = (const float*)d_in[18];
    const float* g2  = (const float*)d_in[19]; const float* b2  = (const float*)d_in[20];

    char* base = (char*)d_ws;
    ushort* agg       = (ushort*)(base);               // bf16 [N,128] = 12.8 MB
    ushort* Qb        = (ushort*)(base + 12800000);    // bf16 [N,128] = 12.8 MB
    uint*   KVp       = (uint*)(base + 25600000);      // uint [N,128] = 25.6 MB (K lo | V hi)
    ushort* ebs_sorted= (ushort*)(base + 51200000);    // bf16 [E,8] = 12.8 MB (CSR order)
    int*    col_sorted= (int*)(base + 64000000);       // [E] = 3.2 MB
    int*    rank      = (int*)(base + 67200000);       // [E] = 3.2 MB
    int*    counts    = (int*)(base + 70400000);       // [N]
    int*    rowstart  = (int*)(base + 70600000);       // [N]
    ushort* wt4       = (ushort*)(base + 70800016);    // [512][128] (Wq|Wk|Wv|Wo)^T
    ushort* w1t       = (ushort*)(base + 70931088);    // [512][128]
    ushort* w2t       = (ushort*)(base + 71062160);    // [128][512]
    ushort* wet       = (ushort*)(base + 71193232);    // [16][128]
    float*  b384      = (float*)(base + 71197328);     // [384]
    int*    blocksum  = (int*)(base + 71198864);       // [196]
    int*    blockoff  = (int*)(base + 71199648);       // [196]
    // peak ~71.2 MB

    zero_counts<<<(NNODES + 255) / 256, 256, 0, stream>>>(counts);

    setup_kernel<<<NEDGES / 256 + 778, 256, 0, stream>>>(ei, counts, rank, Wq, Wk, Wv, Wo,
                                                         W1, W2, We, bq, bk, bv,
                                                         wt4, w1t, w2t, wet, b384);

    dim3 g128((NNODES + 63) / 64, 1);
    ln_qkv_kernel<<<g128, 256, 0, stream>>>(x, g1, b1, wt4, b384, Qb, KVp, NNODES);

    scan_ph1<<<SCAN_BLOCKS, 256, 0, stream>>>(counts, rowstart, blocksum);
    scan_ph2<<<1, 256, 0, stream>>>(blocksum, blockoff);

    edge_bias_scatter<<<2048, 256, 0, stream>>>(ea, wet, be, ei, rowstart, blockoff, rank,
                                                ebs_sorted, col_sorted);
    attn_node_kernel<<<(NNODES + 3) / 4, 256, 0, stream>>>(rowstart, blockoff, col_sorted,
                                                           ebs_sorted, Qb, KVp, agg);

    wo_ffn_kernel<<<g128, 256, 0, stream>>>(agg, wt4 + 49152, bo, x, g2, b2,
                                            w1t, bf1, w2t, bf2, (float*)d_out, NNODES);
}